// Round 14
// baseline (200.658 us; speedup 1.0000x reference)
//
#include <hip/hip_runtime.h>

typedef __attribute__((ext_vector_type(4))) float f32x4;
typedef __attribute__((ext_vector_type(8))) short bf16x8;

__device__ __forceinline__ unsigned short f2b(float f) {
  unsigned u = __float_as_uint(f);
  u = (u + 0x7FFFu + ((u >> 16) & 1u)) >> 16;
  return (unsigned short)u;
}

#define BAR() asm volatile("s_barrier" ::: "memory")
#define VMCNT(N) asm volatile("s_waitcnt vmcnt(" #N ")" ::: "memory")

// ---------------- K1: {selector + skill-mix} ∪ {W f32->bf16} ----------------
__global__ void combine_wconv_kernel(const float* __restrict__ logits,   // [32][8]
                                     const int*   __restrict__ tasks,    // [8]
                                     const float* __restrict__ A,        // [8][2048][16]
                                     const float* __restrict__ B,        // [8][16][2048]
                                     const float* __restrict__ W,        // [2048][2048]
                                     unsigned short* __restrict__ Art,   // [8][16][2048]
                                     unsigned short* __restrict__ Brt,   // [8][2048][16]
                                     unsigned short* __restrict__ Wb)    // [2048][2048]
{
  int blk = blockIdx.x;
  int tid = threadIdx.x;
  if (blk >= 64) {
    int idx0 = (blk - 64) * 256 + tid;
    #pragma unroll
    for (int c = 0; c < 32; ++c) {
      size_t i = ((size_t)idx0 + (size_t)c * 32768) * 4;
      f32x4 v = *(const f32x4*)(W + i);
      ushort4 o;
      o.x = f2b(v.x); o.y = f2b(v.y); o.z = f2b(v.z); o.w = f2b(v.w);
      *(ushort4*)(Wb + i) = o;
    }
    return;
  }
  int idx = blk * 256 + tid;
  int b = idx >> 11;
  int i = idx & 2047;
  int task = tasks[b];
  float p[8]; float s = 0.f;
  #pragma unroll
  for (int t = 0; t < 8; ++t) {
    float l = logits[task * 8 + t];
    float e = 1.f / (1.f + __expf(-l));
    p[t] = e; s += e;
  }
  float inv = 1.f / (s + 1e-12f);
  #pragma unroll
  for (int t = 0; t < 8; ++t) p[t] *= inv;

  float ar[16];
  #pragma unroll
  for (int r = 0; r < 16; ++r) ar[r] = 0.f;
  for (int t = 0; t < 8; ++t) {
    const float* ap = A + ((size_t)t * 2048 + i) * 16;
    float pt = p[t];
    #pragma unroll
    for (int r = 0; r < 16; ++r) ar[r] += pt * ap[r];
  }
  #pragma unroll
  for (int r = 0; r < 16; ++r)
    Art[((size_t)b * 16 + r) * 2048 + i] = f2b(ar[r]);

  float br[16];
  #pragma unroll
  for (int r = 0; r < 16; ++r) br[r] = 0.f;
  for (int t = 0; t < 8; ++t) {
    float pt = p[t];
    #pragma unroll
    for (int r = 0; r < 16; ++r) br[r] += pt * B[((size_t)t * 16 + r) * 2048 + i];
  }
  #pragma unroll
  for (int r = 0; r < 16; ++r)
    Brt[((size_t)b * 2048 + i) * 16 + r] = f2b(br[r] * 0.0625f);
}

// ---------------- K2: prep = x f32->bf16 + xa = x@A_mix ----------------
__global__ void prep_kernel(const float* __restrict__ x,            // [16384][2048]
                            const unsigned short* __restrict__ Art, // [8][16][2048]
                            unsigned short* __restrict__ xb,        // [16384][2048]
                            unsigned short* __restrict__ xa)        // [16384][16]
{
  __shared__ float red[4][16][16];
  int blk = blockIdx.x;
  int tid = threadIdx.x;
  int lane = tid & 63, wv = tid >> 6;
  int lr = lane & 15, hi = lane >> 4;
  int rowbase = blk * 16;
  int batch = rowbase >> 11;
  int row = rowbase + lr;
  f32x4 acc; acc.x = 0.f; acc.y = 0.f; acc.z = 0.f; acc.w = 0.f;
  const float* xrow = x + (size_t)row * 2048 + wv * 512 + hi * 8;
  unsigned short* xbrow = xb + (size_t)row * 2048 + wv * 512 + hi * 8;
  const unsigned short* artrow = Art + ((size_t)batch * 16 + lr) * 2048 + wv * 512 + hi * 8;
  #pragma unroll
  for (int ks = 0; ks < 16; ++ks) {
    f32x4 v0 = *(const f32x4*)(xrow + ks * 32);
    f32x4 v1 = *(const f32x4*)(xrow + ks * 32 + 4);
    bf16x8 av;
    av[0] = (short)f2b(v0.x); av[1] = (short)f2b(v0.y);
    av[2] = (short)f2b(v0.z); av[3] = (short)f2b(v0.w);
    av[4] = (short)f2b(v1.x); av[5] = (short)f2b(v1.y);
    av[6] = (short)f2b(v1.z); av[7] = (short)f2b(v1.w);
    *(bf16x8*)(xbrow + ks * 32) = av;
    bf16x8 bv = *(const bf16x8*)(artrow + ks * 32);
    acc = __builtin_amdgcn_mfma_f32_16x16x32_bf16(av, bv, acc, 0, 0, 0);
  }
  #pragma unroll
  for (int j = 0; j < 4; ++j) red[wv][hi * 4 + j][lr] = acc[j];
  __syncthreads();
  int rr = tid >> 4, cc = tid & 15;
  float s = red[0][rr][cc] + red[1][rr][cc] + red[2][rr][cc] + red[3][rr][cc];
  xa[(size_t)(rowbase + rr) * 16 + cc] = f2b(s);
}

// ---------------- K3: 128x256 GEMM, 2 blocks/CU (cross-block TLP overlap) ----------------
// 512 thr = 8 waves (2 wr x 4 wc), per-wave 64x64 out -> acc 64 f32 (AGPR) -> ~128 regs/thread
// -> 4 waves/SIMD -> 2 blocks/CU co-resident (the m114 mechanism: block A's MFMA overlaps
// block B's stage/LDS phase; time ~ max, not sum). LDS single-buffered 48KB (A 16K + B 32K)
// -> 2 blocks fit 96KB <= 160KB. Simple 2-barrier loop; intra-block serialization is hidden
// by the co-resident block. Zero-conflict swizzle (validated R2-R13) on both sides.
// Grid: tn = bid&7 -> Wb 1MB stripe L2-pinned per XCD; tm = bid>>3 streams (xb L3-resident).
__global__ __launch_bounds__(512, 4)
void gemm_kernel(const unsigned short* __restrict__ xb,  // [16384][2048] bf16
                 const unsigned short* __restrict__ Wb,  // [2048][2048]  bf16 (row = out col)
                 const float* __restrict__ bias,         // [2048]
                 const unsigned short* __restrict__ xa,  // [16384][16]   bf16
                 const unsigned short* __restrict__ Brt, // [8][2048][16] bf16 (pre-scaled 1/16)
                 float* __restrict__ out)                // [16384][2048] f32
{
  __shared__ __align__(16) char lds[49152];
  const int tid = threadIdx.x;
  const int lane = tid & 63;
  const int wv = tid >> 6;
  const int wr = wv >> 2, wc = wv & 3;     // 2 x 4 waves, each 64x64
  const int lr = lane & 15, hi = lane >> 4;
  const int hi16 = hi * 16;

  const int bid = blockIdx.x;
  const int tn = bid & 7, tm = bid >> 3;   // tm in [0,128)
  const int rowbase = tm * 128, colbase = tn * 256;

  // staging geometry: gload g covers rows row0 + g*64 (row0 = tid>>3), 16B chunk tid&7;
  // (tid+g*512)&7 == tid&7 and (row0+g*64)&7 == row0&7 -> same swizzled source col for all g.
  const int row0 = tid >> 3;
  const int scb_e = (((tid & 7) * 16) ^ ((row0 & 7) << 4)) >> 1;

#define GL16(LDSOFF, GPTR) \
  __builtin_amdgcn_global_load_lds((const __attribute__((address_space(1))) unsigned int*)(GPTR), \
      (__attribute__((address_space(3))) unsigned int*)(lds + (LDSOFF)), 16, 0, 0)

// Full-tile stage: A 128 rows (2 gloads) at [0,16384); B 256 rows (4 gloads) at [16384,49152).
#define STAGE_ALL(KOFF) { \
  const unsigned short* ga_ = xb + (size_t)(rowbase + row0) * 2048 + (KOFF) + scb_e; \
  GL16(tid * 16, ga_); \
  GL16(8192 + tid * 16, ga_ + 64 * 2048); \
  const unsigned short* gb_ = Wb + (size_t)(colbase + row0) * 2048 + (KOFF) + scb_e; \
  GL16(16384 + tid * 16, gb_); \
  GL16(16384 + 8192 + tid * 16, gb_ + 64 * 2048); \
  GL16(16384 + 16384 + tid * 16, gb_ + 128 * 2048); \
  GL16(16384 + 24576 + tid * 16, gb_ + 192 * 2048); \
}

  f32x4 acc[4][4];
  #pragma unroll
  for (int i = 0; i < 4; ++i)
    #pragma unroll
    for (int n = 0; n < 4; ++n) { acc[i][n].x = 0.f; acc[i][n].y = 0.f; acc[i][n].z = 0.f; acc[i][n].w = 0.f; }

  bf16x8 a[4][2];

  for (int kt = 0; kt < 32; ++kt) {
    STAGE_ALL(kt * 64);
    VMCNT(0);
    BAR();                          // stage visible to all waves

    // A frags: row ar = wr*64 + mf*16 + lr, swizzled col
    #pragma unroll
    for (int mf = 0; mf < 4; ++mf) {
      int ar = wr * 64 + mf * 16 + lr;
      #pragma unroll
      for (int kk = 0; kk < 2; ++kk)
        a[mf][kk] = *(const bf16x8*)(lds + ar * 128 + ((kk * 64 + hi16) ^ ((ar & 7) << 4)));
    }
    // per n-frag: read B pair, 8 MFMA
    #pragma unroll
    for (int nf = 0; nf < 4; ++nf) {
      int br = wc * 64 + nf * 16 + lr;
      bf16x8 b0 = *(const bf16x8*)(lds + 16384 + br * 128 + ((hi16) ^ ((br & 7) << 4)));
      bf16x8 b1 = *(const bf16x8*)(lds + 16384 + br * 128 + ((64 + hi16) ^ ((br & 7) << 4)));
      __builtin_amdgcn_s_setprio(1);
      #pragma unroll
      for (int mf = 0; mf < 4; ++mf) {
        acc[mf][nf] = __builtin_amdgcn_mfma_f32_16x16x32_bf16(a[mf][0], b0, acc[mf][nf], 0, 0, 0);
        acc[mf][nf] = __builtin_amdgcn_mfma_f32_16x16x32_bf16(a[mf][1], b1, acc[mf][nf], 0, 0, 0);
      }
      __builtin_amdgcn_s_setprio(0);
    }
    BAR();                          // all reads done -> next stage may overwrite
  }

  // ---- LoRA epilogue: zero-padded 16x16x32 MFMA per frag (rank 16 in K=32) ----
  const int batch = rowbase >> 11;
  bf16x8 zf = (bf16x8)(short)0;
  bf16x8 ea[4], eb[4];
  #pragma unroll
  for (int i = 0; i < 4; ++i) {
    if (hi < 2)
      ea[i] = *(const bf16x8*)(xa + (size_t)(rowbase + wr * 64 + i * 16 + lr) * 16 + hi * 8);
    else
      ea[i] = zf;
  }
  #pragma unroll
  for (int n = 0; n < 4; ++n) {
    if (hi < 2)
      eb[n] = *(const bf16x8*)(Brt + ((size_t)batch * 2048 + colbase + wc * 64 + n * 16 + lr) * 16 + hi * 8);
    else
      eb[n] = zf;
  }
  #pragma unroll
  for (int i = 0; i < 4; ++i)
    #pragma unroll
    for (int n = 0; n < 4; ++n)
      acc[i][n] = __builtin_amdgcn_mfma_f32_16x16x32_bf16(ea[i], eb[n], acc[i][n], 0, 0, 0);

  // ---- bias + store (C/D: col = lane&15, row = (lane>>4)*4 + j) ----
  #pragma unroll
  for (int n = 0; n < 4; ++n) {
    int col = colbase + wc * 64 + n * 16 + lr;
    float bbv = bias[col];
    #pragma unroll
    for (int i = 0; i < 4; ++i) {
      int r0 = rowbase + wr * 64 + i * 16 + hi * 4;
      #pragma unroll
      for (int j = 0; j < 4; ++j)
        out[(size_t)(r0 + j) * 2048 + col] = acc[i][n][j] + bbv;
    }
  }
#undef GL16
#undef STAGE_ALL
}

extern "C" void kernel_launch(void* const* d_in, const int* in_sizes, int n_in,
                              void* d_out, int out_size, void* d_ws, size_t ws_size,
                              hipStream_t stream) {
  const float* x      = (const float*)d_in[0];   // [8][2048][2048]
  const float* W      = (const float*)d_in[1];   // [2048][2048]
  const float* bias   = (const float*)d_in[2];   // [2048]
  const float* logits = (const float*)d_in[3];   // [32][8]
  const float* A      = (const float*)d_in[4];   // [1][8][2048][16]
  const float* B      = (const float*)d_in[5];   // [1][8][16][2048]
  const int*   tasks  = (const int*)d_in[6];     // [8]
  float* out = (float*)d_out;

  char* ws = (char*)d_ws;
  unsigned short* xb  = (unsigned short*)(ws);                         // 67108864 B
  unsigned short* Wb  = (unsigned short*)(ws + 67108864);              //  8388608 B
  unsigned short* xa  = (unsigned short*)(ws + 67108864 + 8388608);    //   524288 B
  unsigned short* Art = (unsigned short*)(ws + 67108864 + 8388608 + 524288);
  unsigned short* Brt = (unsigned short*)(ws + 67108864 + 8388608 + 1048576);

  combine_wconv_kernel<<<192, 256, 0, stream>>>(logits, tasks, A, B, W, Art, Brt, Wb);
  prep_kernel<<<1024, 256, 0, stream>>>(x, Art, xb, xa);
  gemm_kernel<<<1024, 512, 0, stream>>>(xb, Wb, bias, xa, Brt, out);
}